// Round 1
// baseline (18160.564 us; speedup 1.0000x reference)
//
#include <hip/hip_runtime.h>
#include <math.h>

#define H       256
#define TB      32      // samples per workgroup
#define NT      256     // threads per workgroup
#define NSTEPS  32
#define XPAD    260     // H + 4 padding to break LDS bank alignment across rows

// fast tanh via hardware exp; error ~1e-6, and the MLP output is scaled by
// ~5e-5 before touching the state, so this is far inside tolerance.
__device__ __forceinline__ float fast_tanh(float x) {
    x = fminf(fmaxf(x, -15.0f), 15.0f);
    float e = __expf(2.0f * x);
    return 1.0f - 2.0f / (e + 1.0f);
}

// acc[ii][jj] = sum_k Xin[i0+ii][k] * W[(j0+jj)*H + k]      (forward: y = x @ W^T)
__device__ __forceinline__ void matdot_fwd(const float (*Xin)[XPAD],
                                           const float* __restrict__ W,
                                           int i0, int j0, float acc[4][8]) {
    #pragma unroll
    for (int ii = 0; ii < 4; ++ii)
        #pragma unroll
        for (int jj = 0; jj < 8; ++jj)
            acc[ii][jj] = 0.0f;
    const float* wrow[8];
    #pragma unroll
    for (int jj = 0; jj < 8; ++jj) wrow[jj] = W + (size_t)(j0 + jj) * H;
    for (int k = 0; k < H; k += 4) {
        float x[4][4];
        #pragma unroll
        for (int ii = 0; ii < 4; ++ii) {
            float4 v = *reinterpret_cast<const float4*>(&Xin[i0 + ii][k]);
            x[ii][0] = v.x; x[ii][1] = v.y; x[ii][2] = v.z; x[ii][3] = v.w;
        }
        #pragma unroll
        for (int jj = 0; jj < 8; ++jj) {
            float4 w = *reinterpret_cast<const float4*>(wrow[jj] + k);
            #pragma unroll
            for (int ii = 0; ii < 4; ++ii)
                acc[ii][jj] += x[ii][0] * w.x + x[ii][1] * w.y
                             + x[ii][2] * w.z + x[ii][3] * w.w;
        }
    }
}

// acc[ii][jj] = sum_j Xin[i0+ii][j] * W[j*H + (j0+jj)]      (backward: y = u @ W)
__device__ __forceinline__ void matdot_bwd(const float (*Xin)[XPAD],
                                           const float* __restrict__ W,
                                           int i0, int j0, float acc[4][8]) {
    #pragma unroll
    for (int ii = 0; ii < 4; ++ii)
        #pragma unroll
        for (int jj = 0; jj < 8; ++jj)
            acc[ii][jj] = 0.0f;
    for (int j = 0; j < H; j += 4) {
        float x[4][4];
        #pragma unroll
        for (int ii = 0; ii < 4; ++ii) {
            float4 v = *reinterpret_cast<const float4*>(&Xin[i0 + ii][j]);
            x[ii][0] = v.x; x[ii][1] = v.y; x[ii][2] = v.z; x[ii][3] = v.w;
        }
        #pragma unroll
        for (int jo = 0; jo < 4; ++jo) {
            const float* wr = W + (size_t)(j + jo) * H + j0;
            float4 wa = *reinterpret_cast<const float4*>(wr);
            float4 wb = *reinterpret_cast<const float4*>(wr + 4);
            #pragma unroll
            for (int ii = 0; ii < 4; ++ii) {
                float xv = x[ii][jo];
                acc[ii][0] += xv * wa.x; acc[ii][1] += xv * wa.y;
                acc[ii][2] += xv * wa.z; acc[ii][3] += xv * wa.w;
                acc[ii][4] += xv * wb.x; acc[ii][5] += xv * wb.y;
                acc[ii][6] += xv * wb.z; acc[ii][7] += xv * wb.w;
            }
        }
    }
}

__global__ __launch_bounds__(NT, 2)
void sympnet_kernel(const float* __restrict__ t_eval,
                    const float* __restrict__ state0,
                    const float* __restrict__ W1, const float* __restrict__ b1,
                    const float* __restrict__ W2, const float* __restrict__ b2,
                    const float* __restrict__ W3, const float* __restrict__ b3,
                    const float* __restrict__ W4,
                    const float* __restrict__ scale_p,
                    float* __restrict__ out)
{
    __shared__ float sS[TB][4];
    __shared__ float Xa[TB][XPAD];   // ping
    __shared__ float Xb[TB][XPAD];   // pong
    __shared__ float gp[TB][8][4];   // partial gradients
    __shared__ float G[TB][4];       // reduced gradient dH/ds

    const int tid = threadIdx.x;
    const int b0  = blockIdx.x * TB;
    const int j0  = (tid & 31) * 8;  // 8 consecutive hidden outputs
    const int i0  = (tid >> 5) * 4;  // 4 consecutive samples

    const float dt    = t_eval[1] - t_eval[0];
    const float scale = scale_p[0];

    // load state0, emit t=0
    if (tid < TB) {
        float4 s = reinterpret_cast<const float4*>(state0)[b0 + tid];
        sS[tid][0] = s.x; sS[tid][1] = s.y; sS[tid][2] = s.z; sS[tid][3] = s.w;
        reinterpret_cast<float4*>(out)[(size_t)(b0 + tid) * NSTEPS] = s;
    }
    __syncthreads();

    float h1r[4][8], h2r[4][8], acc[4][8];

    for (int t = 1; t < NSTEPS; ++t) {
        // ---- L1: h1 = tanh(s @ W1^T + b1) -> regs + Xa
        {
            float4 wv[8];
            #pragma unroll
            for (int jj = 0; jj < 8; ++jj)
                wv[jj] = reinterpret_cast<const float4*>(W1)[j0 + jj];
            float bb[8];
            {
                float4 a = *reinterpret_cast<const float4*>(&b1[j0]);
                float4 b = *reinterpret_cast<const float4*>(&b1[j0 + 4]);
                bb[0]=a.x; bb[1]=a.y; bb[2]=a.z; bb[3]=a.w;
                bb[4]=b.x; bb[5]=b.y; bb[6]=b.z; bb[7]=b.w;
            }
            #pragma unroll
            for (int ii = 0; ii < 4; ++ii) {
                float4 sv = *reinterpret_cast<const float4*>(&sS[i0 + ii][0]);
                float row[8];
                #pragma unroll
                for (int jj = 0; jj < 8; ++jj) {
                    float z = bb[jj] + sv.x * wv[jj].x + sv.y * wv[jj].y
                                     + sv.z * wv[jj].z + sv.w * wv[jj].w;
                    float h = fast_tanh(z);
                    h1r[ii][jj] = h;
                    row[jj] = h;
                }
                *reinterpret_cast<float4*>(&Xa[i0 + ii][j0])     = make_float4(row[0], row[1], row[2], row[3]);
                *reinterpret_cast<float4*>(&Xa[i0 + ii][j0 + 4]) = make_float4(row[4], row[5], row[6], row[7]);
            }
        }
        __syncthreads();

        // ---- L2: h2 = tanh(h1 @ W2^T + b2) -> regs + Xb
        matdot_fwd(Xa, W2, i0, j0, acc);
        {
            float bb[8];
            float4 a = *reinterpret_cast<const float4*>(&b2[j0]);
            float4 b = *reinterpret_cast<const float4*>(&b2[j0 + 4]);
            bb[0]=a.x; bb[1]=a.y; bb[2]=a.z; bb[3]=a.w;
            bb[4]=b.x; bb[5]=b.y; bb[6]=b.z; bb[7]=b.w;
            #pragma unroll
            for (int ii = 0; ii < 4; ++ii) {
                float row[8];
                #pragma unroll
                for (int jj = 0; jj < 8; ++jj) {
                    float h = fast_tanh(acc[ii][jj] + bb[jj]);
                    h2r[ii][jj] = h;
                    row[jj] = h;
                }
                *reinterpret_cast<float4*>(&Xb[i0 + ii][j0])     = make_float4(row[0], row[1], row[2], row[3]);
                *reinterpret_cast<float4*>(&Xb[i0 + ii][j0 + 4]) = make_float4(row[4], row[5], row[6], row[7]);
            }
        }
        __syncthreads();

        // ---- L3: h3 = tanh(h2 @ W3^T + b3); u3 = W4 * (1 - h3^2) -> Xa
        matdot_fwd(Xb, W3, i0, j0, acc);
        {
            float bb[8], w4[8];
            float4 a = *reinterpret_cast<const float4*>(&b3[j0]);
            float4 b = *reinterpret_cast<const float4*>(&b3[j0 + 4]);
            bb[0]=a.x; bb[1]=a.y; bb[2]=a.z; bb[3]=a.w;
            bb[4]=b.x; bb[5]=b.y; bb[6]=b.z; bb[7]=b.w;
            float4 wa = *reinterpret_cast<const float4*>(&W4[j0]);
            float4 wb = *reinterpret_cast<const float4*>(&W4[j0 + 4]);
            w4[0]=wa.x; w4[1]=wa.y; w4[2]=wa.z; w4[3]=wa.w;
            w4[4]=wb.x; w4[5]=wb.y; w4[6]=wb.z; w4[7]=wb.w;
            #pragma unroll
            for (int ii = 0; ii < 4; ++ii) {
                float row[8];
                #pragma unroll
                for (int jj = 0; jj < 8; ++jj) {
                    float h = fast_tanh(acc[ii][jj] + bb[jj]);
                    row[jj] = w4[jj] * (1.0f - h * h);
                }
                *reinterpret_cast<float4*>(&Xa[i0 + ii][j0])     = make_float4(row[0], row[1], row[2], row[3]);
                *reinterpret_cast<float4*>(&Xa[i0 + ii][j0 + 4]) = make_float4(row[4], row[5], row[6], row[7]);
            }
        }
        __syncthreads();

        // ---- B1: u2 = (u3 @ W3) * (1 - h2^2) -> Xb
        matdot_bwd(Xa, W3, i0, j0, acc);
        #pragma unroll
        for (int ii = 0; ii < 4; ++ii) {
            float row[8];
            #pragma unroll
            for (int jj = 0; jj < 8; ++jj) {
                float h = h2r[ii][jj];
                row[jj] = acc[ii][jj] * (1.0f - h * h);
            }
            *reinterpret_cast<float4*>(&Xb[i0 + ii][j0])     = make_float4(row[0], row[1], row[2], row[3]);
            *reinterpret_cast<float4*>(&Xb[i0 + ii][j0 + 4]) = make_float4(row[4], row[5], row[6], row[7]);
        }
        __syncthreads();

        // ---- B2: u1 = (u2 @ W2) * (1 - h1^2) -> Xa
        matdot_bwd(Xb, W2, i0, j0, acc);
        #pragma unroll
        for (int ii = 0; ii < 4; ++ii) {
            float row[8];
            #pragma unroll
            for (int jj = 0; jj < 8; ++jj) {
                float h = h1r[ii][jj];
                row[jj] = acc[ii][jj] * (1.0f - h * h);
            }
            *reinterpret_cast<float4*>(&Xa[i0 + ii][j0])     = make_float4(row[0], row[1], row[2], row[3]);
            *reinterpret_cast<float4*>(&Xa[i0 + ii][j0 + 4]) = make_float4(row[4], row[5], row[6], row[7]);
        }
        __syncthreads();

        // ---- B3: g[i][c] = sum_k u1[i][k] * W1[k][c]   (partial per 32-k slice)
        {
            const int i  = tid >> 3;      // 0..31
            const int sl = tid & 7;       // 0..7
            const int kb = sl * 32;
            float p0 = 0.f, p1 = 0.f, p2 = 0.f, p3 = 0.f;
            for (int k = kb; k < kb + 32; k += 4) {
                float4 u = *reinterpret_cast<const float4*>(&Xa[i][k]);
                float4 w0 = reinterpret_cast<const float4*>(W1)[k];
                float4 w1 = reinterpret_cast<const float4*>(W1)[k + 1];
                float4 w2 = reinterpret_cast<const float4*>(W1)[k + 2];
                float4 w3 = reinterpret_cast<const float4*>(W1)[k + 3];
                p0 += u.x * w0.x + u.y * w1.x + u.z * w2.x + u.w * w3.x;
                p1 += u.x * w0.y + u.y * w1.y + u.z * w2.y + u.w * w3.y;
                p2 += u.x * w0.z + u.y * w1.z + u.z * w2.z + u.w * w3.z;
                p3 += u.x * w0.w + u.y * w1.w + u.z * w2.w + u.w * w3.w;
            }
            gp[i][sl][0] = p0; gp[i][sl][1] = p1; gp[i][sl][2] = p2; gp[i][sl][3] = p3;
        }
        __syncthreads();
        if (tid < 128) {
            const int i = tid >> 2, c = tid & 3;
            float s = 0.f;
            #pragma unroll
            for (int sl = 0; sl < 8; ++sl) s += gp[i][sl][c];
            G[i][c] = s;
        }
        __syncthreads();

        // ---- state update: verlet + adaptive correction; emit trajectory row
        if (tid < TB) {
            float q1  = sS[tid][0], p1v = sS[tid][1];
            float q2  = sS[tid][2], p2v = sS[tid][3];
            float g0 = G[tid][0], g1 = G[tid][1], g2 = G[tid][2], g3 = G[tid][3];
            float c0 = g1, c1 = -g0, c2 = g3, c3 = -g2;
            float nrm = sqrtf(c0*c0 + c1*c1 + c2*c2 + c3*c3);
            float ad  = dt * fminf(fmaxf(1.0f - 0.1f * nrm, 0.5f), 1.0f);
            // velocity-Verlet
            float F1  = -q1 * (1.0f + 2.0f * q2);
            float F2  = -(q2 + q1 * q1 - q2 * q2);
            float p1h = p1v + 0.5f * dt * F1;
            float p2h = p2v + 0.5f * dt * F2;
            float q1n = q1 + dt * p1h;
            float q2n = q2 + dt * p2h;
            float F1n = -q1n * (1.0f + 2.0f * q2n);
            float F2n = -(q2n + q1n * q1n - q2n * q2n);
            float p1n = p1h + 0.5f * dt * F1n;
            float p2n = p2h + 0.5f * dt * F2n;
            float as  = ad * scale;
            float ns0 = q1n + as * c0;
            float ns1 = p1n + as * c1;
            float ns2 = q2n + as * c2;
            float ns3 = p2n + as * c3;
            sS[tid][0] = ns0; sS[tid][1] = ns1; sS[tid][2] = ns2; sS[tid][3] = ns3;
            reinterpret_cast<float4*>(out)[(size_t)(b0 + tid) * NSTEPS + t] =
                make_float4(ns0, ns1, ns2, ns3);
        }
        __syncthreads();
    }
}

extern "C" void kernel_launch(void* const* d_in, const int* in_sizes, int n_in,
                              void* d_out, int out_size, void* d_ws, size_t ws_size,
                              hipStream_t stream) {
    const float* t_eval = (const float*)d_in[0];
    const float* state0 = (const float*)d_in[1];
    const float* W1     = (const float*)d_in[2];
    const float* b1     = (const float*)d_in[3];
    const float* W2     = (const float*)d_in[4];
    const float* b2     = (const float*)d_in[5];
    const float* W3     = (const float*)d_in[6];
    const float* b3     = (const float*)d_in[7];
    const float* W4     = (const float*)d_in[8];
    // d_in[9] = b4: drops out of the gradient; unused
    const float* scale  = (const float*)d_in[10];
    float* out = (float*)d_out;

    const int batch = in_sizes[1] / 4;          // 32768
    dim3 grid(batch / TB), block(NT);
    sympnet_kernel<<<grid, block, 0, stream>>>(t_eval, state0, W1, b1, W2, b2,
                                               W3, b3, W4, scale, out);
}

// Round 2
// 6727.714 us; speedup vs baseline: 2.6994x; 2.6994x over previous
//
#include <hip/hip_runtime.h>
#include <math.h>

#define H       256
#define TB      32      // samples per workgroup
#define NT      256     // threads per workgroup (4 waves)
#define NSTEPS  32
#define XS      264     // bf16 elems per activation row: 528B, 16B-aligned, low-conflict
#define DS1     260     // bf16 elems per d1 row: 520B, 8B-aligned

typedef __attribute__((ext_vector_type(8)))  short short8v;   // MFMA A/B frag: 8 bf16
typedef __attribute__((ext_vector_type(16))) float f32x16;    // MFMA C/D frag

__device__ __forceinline__ float fast_tanh(float x) {
    x = fminf(fmaxf(x, -15.0f), 15.0f);
    float e = __expf(2.0f * x);
    return 1.0f - 2.0f / (e + 1.0f);
}

// fp32 -> bf16 bits, round-to-nearest-even
__device__ __forceinline__ unsigned short f2b(float x) {
    unsigned u = __float_as_uint(x);
    u += 0x7FFFu + ((u >> 16) & 1u);
    return (unsigned short)(u >> 16);
}
__device__ __forceinline__ float b2f(unsigned short h) {
    return __uint_as_float(((unsigned)h) << 16);
}

// ---- pre-pass: fp32 W2,W3 -> bf16 row-major + transposed copies in d_ws ----
// ws layout (bf16 elems): W2b[0,64K) W3b[64K,128K) W2Tb[128K,192K) W3Tb[192K,256K)
__global__ void convert_w(const float* __restrict__ W2, const float* __restrict__ W3,
                          unsigned short* __restrict__ wsb) {
    int t = blockIdx.x * blockDim.x + threadIdx.x;   // 0..65535
    int i = t >> 8, j = t & 255;
    float w2 = W2[t], w3 = W3[t];
    wsb[t]                         = f2b(w2);
    wsb[65536 + t]                 = f2b(w3);
    wsb[131072 + (j << 8) + i]     = f2b(w2);   // W2T[j][i] = W2[i][j]
    wsb[196608 + (j << 8) + i]     = f2b(w3);
}

// one 32x32 output tile: C[n0+row][m] = sum_k Wg[n0+row][k] * X[m][k]
// A = weights (global bf16 row-major), B = activations (LDS, preloaded frags)
__device__ __forceinline__ f32x16 tile_mfma(const short* __restrict__ Wg, int n0,
                                            int col, int q, const short8v* bvv) {
    f32x16 acc = {};
    const short* ap = Wg + ((n0 + col) << 8) + q * 8;
    #pragma unroll
    for (int kc = 0; kc < 16; ++kc) {
        short8v a = *reinterpret_cast<const short8v*>(ap + kc * 16);
        acc = __builtin_amdgcn_mfma_f32_32x32x16_bf16(a, bvv[kc], acc, 0, 0, 0);
    }
    return acc;
}

#define LOAD_BV(Xsrc)                                                          \
    short8v bvv[16];                                                           \
    _Pragma("unroll")                                                          \
    for (int kc = 0; kc < 16; ++kc)                                            \
        bvv[kc] = *reinterpret_cast<const short8v*>(&Xsrc[col][kc * 16 + q * 8]);

__global__ __launch_bounds__(NT, 3)
void sympnet_mfma(const float* __restrict__ t_eval,
                  const float* __restrict__ state0,
                  const float* __restrict__ W1, const float* __restrict__ b1,
                  const float* __restrict__ b2, const float* __restrict__ b3,
                  const float* __restrict__ W4, const float* __restrict__ scale_p,
                  const short* __restrict__ W2b,  const short* __restrict__ W3b,
                  const short* __restrict__ W2Tb, const short* __restrict__ W3Tb,
                  float* __restrict__ out)
{
    __shared__ unsigned short Xa[TB][XS];
    __shared__ unsigned short Xb[TB][XS];
    __shared__ unsigned short D1[TB][DS1];   // (1 - h1^2) bf16
    __shared__ float sS[TB][4];
    __shared__ float gp[4][TB][4];           // per-wave gradient partials

    const int tid  = threadIdx.x;
    const int lane = tid & 63;
    const int wv   = tid >> 6;      // wave 0..3
    const int col  = lane & 31;     // MFMA lane&31 index (M for A-frag, N for B/C)
    const int q    = lane >> 5;

    const float dt    = t_eval[1] - t_eval[0];
    const float scale = scale_p[0];
    const int   b0    = blockIdx.x * TB;

    if (tid < TB) {
        float4 s = reinterpret_cast<const float4*>(state0)[b0 + tid];
        sS[tid][0] = s.x; sS[tid][1] = s.y; sS[tid][2] = s.z; sS[tid][3] = s.w;
        reinterpret_cast<float4*>(out)[(size_t)(b0 + tid) * NSTEPS] = s;
    }
    __syncthreads();

    float d2[32];   // (1 - h2^2) for this wave's two tiles, in registers

    for (int t = 1; t < NSTEPS; ++t) {
        // ================= L1 (VALU): h1 = tanh(s @ W1^T + b1) -> Xa, D1
        {
            const int j0  = (tid & 31) * 8;
            const int i0v = (tid >> 5) * 4;
            float4 wvv[8];
            #pragma unroll
            for (int jj = 0; jj < 8; ++jj)
                wvv[jj] = reinterpret_cast<const float4*>(W1)[j0 + jj];
            float bb[8];
            {
                float4 a = *reinterpret_cast<const float4*>(&b1[j0]);
                float4 b = *reinterpret_cast<const float4*>(&b1[j0 + 4]);
                bb[0]=a.x; bb[1]=a.y; bb[2]=a.z; bb[3]=a.w;
                bb[4]=b.x; bb[5]=b.y; bb[6]=b.z; bb[7]=b.w;
            }
            #pragma unroll
            for (int ii = 0; ii < 4; ++ii) {
                float4 sv = *reinterpret_cast<const float4*>(&sS[i0v + ii][0]);
                unsigned short hb[8], db[8];
                #pragma unroll
                for (int jj = 0; jj < 8; ++jj) {
                    float z = bb[jj] + sv.x * wvv[jj].x + sv.y * wvv[jj].y
                                     + sv.z * wvv[jj].z + sv.w * wvv[jj].w;
                    float h = fast_tanh(z);
                    hb[jj] = f2b(h);
                    db[jj] = f2b(fmaf(-h, h, 1.0f));
                }
                *reinterpret_cast<short4*>(&Xa[i0v + ii][j0]) =
                    make_short4(hb[0], hb[1], hb[2], hb[3]);
                *reinterpret_cast<short4*>(&Xa[i0v + ii][j0 + 4]) =
                    make_short4(hb[4], hb[5], hb[6], hb[7]);
                *reinterpret_cast<short4*>(&D1[i0v + ii][j0]) =
                    make_short4(db[0], db[1], db[2], db[3]);
                *reinterpret_cast<short4*>(&D1[i0v + ii][j0 + 4]) =
                    make_short4(db[4], db[5], db[6], db[7]);
            }
        }
        __syncthreads();

        // ================= L2 (MFMA): h2 = tanh(W2 h1 + b2) -> Xb, d2 regs
        {
            LOAD_BV(Xa);
            #pragma unroll
            for (int ti = 0; ti < 2; ++ti) {
                const int n0 = wv * 64 + ti * 32;
                float4 bv4[4];
                #pragma unroll
                for (int g = 0; g < 4; ++g)
                    bv4[g] = *reinterpret_cast<const float4*>(&b2[n0 + 8*g + 4*q]);
                f32x16 acc = tile_mfma(W2b, n0, col, q, bvv);
                #pragma unroll
                for (int g = 0; g < 4; ++g) {
                    const float* bp = reinterpret_cast<const float*>(&bv4[g]);
                    unsigned short hb[4];
                    #pragma unroll
                    for (int rr = 0; rr < 4; ++rr) {
                        float h = fast_tanh(acc[4*g + rr] + bp[rr]);
                        d2[ti*16 + 4*g + rr] = fmaf(-h, h, 1.0f);
                        hb[rr] = f2b(h);
                    }
                    *reinterpret_cast<short4*>(&Xb[col][n0 + 8*g + 4*q]) =
                        make_short4(hb[0], hb[1], hb[2], hb[3]);
                }
            }
        }
        __syncthreads();

        // ================= L3 (MFMA): u3 = W4 ⊙ (1 - tanh^2(W3 h2 + b3)) -> Xa
        {
            LOAD_BV(Xb);
            #pragma unroll
            for (int ti = 0; ti < 2; ++ti) {
                const int n0 = wv * 64 + ti * 32;
                float4 bv4[4], wv4[4];
                #pragma unroll
                for (int g = 0; g < 4; ++g) {
                    bv4[g] = *reinterpret_cast<const float4*>(&b3[n0 + 8*g + 4*q]);
                    wv4[g] = *reinterpret_cast<const float4*>(&W4[n0 + 8*g + 4*q]);
                }
                f32x16 acc = tile_mfma(W3b, n0, col, q, bvv);
                #pragma unroll
                for (int g = 0; g < 4; ++g) {
                    const float* bp = reinterpret_cast<const float*>(&bv4[g]);
                    const float* wp = reinterpret_cast<const float*>(&wv4[g]);
                    unsigned short ub[4];
                    #pragma unroll
                    for (int rr = 0; rr < 4; ++rr) {
                        float h = fast_tanh(acc[4*g + rr] + bp[rr]);
                        ub[rr] = f2b(wp[rr] * fmaf(-h, h, 1.0f));
                    }
                    *reinterpret_cast<short4*>(&Xa[col][n0 + 8*g + 4*q]) =
                        make_short4(ub[0], ub[1], ub[2], ub[3]);
                }
            }
        }
        __syncthreads();

        // ================= B1 (MFMA): u2 = (W3^T u3) ⊙ d2 -> Xb
        {
            LOAD_BV(Xa);
            #pragma unroll
            for (int ti = 0; ti < 2; ++ti) {
                const int n0 = wv * 64 + ti * 32;
                f32x16 acc = tile_mfma(W3Tb, n0, col, q, bvv);
                #pragma unroll
                for (int g = 0; g < 4; ++g) {
                    unsigned short ub[4];
                    #pragma unroll
                    for (int rr = 0; rr < 4; ++rr)
                        ub[rr] = f2b(acc[4*g + rr] * d2[ti*16 + 4*g + rr]);
                    *reinterpret_cast<short4*>(&Xb[col][n0 + 8*g + 4*q]) =
                        make_short4(ub[0], ub[1], ub[2], ub[3]);
                }
            }
        }
        __syncthreads();

        // ===== B2 (MFMA) + B3 fold: u1 = (W2^T u2) ⊙ d1; g[m][c] += u1·W1[n][c]
        {
            float pg0 = 0.f, pg1 = 0.f, pg2 = 0.f, pg3 = 0.f;
            #pragma unroll
            for (int ti = 0; ti < 2; ++ti) {
                const int n0 = wv * 64 + ti * 32;
                float4 w1v[16];
                #pragma unroll
                for (int g = 0; g < 4; ++g)
                    #pragma unroll
                    for (int rr = 0; rr < 4; ++rr)
                        w1v[4*g + rr] =
                            reinterpret_cast<const float4*>(W1)[n0 + 8*g + 4*q + rr];
                f32x16 acc = {};
                const short* ap = W2Tb + ((n0 + col) << 8) + q * 8;
                #pragma unroll
                for (int kc = 0; kc < 16; ++kc) {
                    short8v a = *reinterpret_cast<const short8v*>(ap + kc * 16);
                    short8v b = *reinterpret_cast<const short8v*>(&Xb[col][kc*16 + q*8]);
                    acc = __builtin_amdgcn_mfma_f32_32x32x16_bf16(a, b, acc, 0, 0, 0);
                }
                #pragma unroll
                for (int g = 0; g < 4; ++g) {
                    short4 dv = *reinterpret_cast<const short4*>(&D1[col][n0 + 8*g + 4*q]);
                    float dd[4] = { b2f((unsigned short)dv.x), b2f((unsigned short)dv.y),
                                    b2f((unsigned short)dv.z), b2f((unsigned short)dv.w) };
                    #pragma unroll
                    for (int rr = 0; rr < 4; ++rr) {
                        float u1 = acc[4*g + rr] * dd[rr];
                        float4 w = w1v[4*g + rr];
                        pg0 = fmaf(u1, w.x, pg0); pg1 = fmaf(u1, w.y, pg1);
                        pg2 = fmaf(u1, w.z, pg2); pg3 = fmaf(u1, w.w, pg3);
                    }
                }
            }
            // combine the two k-halves (q=0,1) within the wave
            pg0 += __shfl_xor(pg0, 32); pg1 += __shfl_xor(pg1, 32);
            pg2 += __shfl_xor(pg2, 32); pg3 += __shfl_xor(pg3, 32);
            if (q == 0)
                *reinterpret_cast<float4*>(&gp[wv][col][0]) =
                    make_float4(pg0, pg1, pg2, pg3);
        }
        __syncthreads();

        // ================= state update (fp32 Verlet + correction)
        if (tid < TB) {
            float g0 = 0.f, g1 = 0.f, g2 = 0.f, g3 = 0.f;
            #pragma unroll
            for (int w = 0; w < 4; ++w) {
                float4 p = *reinterpret_cast<const float4*>(&gp[w][tid][0]);
                g0 += p.x; g1 += p.y; g2 += p.z; g3 += p.w;
            }
            float c0 = g1, c1 = -g0, c2 = g3, c3 = -g2;
            float nrm = sqrtf(c0*c0 + c1*c1 + c2*c2 + c3*c3);
            float ad  = dt * fminf(fmaxf(1.0f - 0.1f * nrm, 0.5f), 1.0f);
            float q1  = sS[tid][0], p1v = sS[tid][1];
            float q2  = sS[tid][2], p2v = sS[tid][3];
            float F1  = -q1 * (1.0f + 2.0f * q2);
            float F2  = -(q2 + q1 * q1 - q2 * q2);
            float p1h = p1v + 0.5f * dt * F1;
            float p2h = p2v + 0.5f * dt * F2;
            float q1n = q1 + dt * p1h;
            float q2n = q2 + dt * p2h;
            float F1n = -q1n * (1.0f + 2.0f * q2n);
            float F2n = -(q2n + q1n * q1n - q2n * q2n);
            float p1n = p1h + 0.5f * dt * F1n;
            float p2n = p2h + 0.5f * dt * F2n;
            float as  = ad * scale;
            float ns0 = q1n + as * c0;
            float ns1 = p1n + as * c1;
            float ns2 = q2n + as * c2;
            float ns3 = p2n + as * c3;
            sS[tid][0] = ns0; sS[tid][1] = ns1; sS[tid][2] = ns2; sS[tid][3] = ns3;
            reinterpret_cast<float4*>(out)[(size_t)(b0 + tid) * NSTEPS + t] =
                make_float4(ns0, ns1, ns2, ns3);
        }
        __syncthreads();
    }
}

extern "C" void kernel_launch(void* const* d_in, const int* in_sizes, int n_in,
                              void* d_out, int out_size, void* d_ws, size_t ws_size,
                              hipStream_t stream) {
    const float* t_eval = (const float*)d_in[0];
    const float* state0 = (const float*)d_in[1];
    const float* W1     = (const float*)d_in[2];
    const float* b1     = (const float*)d_in[3];
    const float* W2     = (const float*)d_in[4];
    const float* b2     = (const float*)d_in[5];
    const float* W3     = (const float*)d_in[6];
    const float* b3     = (const float*)d_in[7];
    const float* W4     = (const float*)d_in[8];
    const float* scale  = (const float*)d_in[10];
    float* out = (float*)d_out;

    unsigned short* wsb = (unsigned short*)d_ws;
    convert_w<<<dim3(256), dim3(256), 0, stream>>>(W2, W3, wsb);

    const short* W2b  = (const short*)(wsb);
    const short* W3b  = (const short*)(wsb + 65536);
    const short* W2Tb = (const short*)(wsb + 131072);
    const short* W3Tb = (const short*)(wsb + 196608);

    const int batch = in_sizes[1] / 4;   // 32768
    sympnet_mfma<<<dim3(batch / TB), dim3(NT), 0, stream>>>(
        t_eval, state0, W1, b1, b2, b3, W4, scale,
        W2b, W3b, W2Tb, W3Tb, out);
}